// Round 12
// baseline (168.825 us; speedup 1.0000x reference)
//
#include <hip/hip_runtime.h>
#include <hip/hip_bf16.h>
#include <stdint.h>

typedef __bf16 bf16x8 __attribute__((ext_vector_type(8)));
typedef float  f32x4  __attribute__((ext_vector_type(4)));

#define M_ROWS 8192
#define K_DIM  2048
#define HIDN   1024
#define BM 128
#define BN 256
#define BK 32
#define NTILES (K_DIM / BK)   /* 64 */
#define NITER  (NTILES / 2)   /* 32 */

__device__ __forceinline__ unsigned short f2bf(float f) {
    __hip_bfloat16 h = __float2bfloat16(f);
    return *reinterpret_cast<unsigned short*>(&h);
}

// ---------------- fused pack kernel (verified) ----------------
__global__ __launch_bounds__(256) void pack_kernel(const float* __restrict__ x,
                                                   const float* __restrict__ h0,
                                                   const float* __restrict__ Wx,
                                                   const float* __restrict__ Wh,
                                                   unsigned short* __restrict__ A,
                                                   unsigned short* __restrict__ Bp) {
    if (blockIdx.x < 16384) {
        int idx = blockIdx.x * 256 + threadIdx.x;
        int row = idx >> 9;
        int col = (idx & 511) << 2;
        const float* src = (col < HIDN) ? (x + (int64_t)row * HIDN + col)
                                        : (h0 + (int64_t)row * HIDN + (col - HIDN));
        float4 v = *reinterpret_cast<const float4*>(src);
        ushort4 o;
        o.x = f2bf(v.x); o.y = f2bf(v.y); o.z = f2bf(v.z); o.w = f2bf(v.w);
        *reinterpret_cast<ushort4*>(A + (int64_t)idx * 4) = o;
    } else {
        int idx = (blockIdx.x - 16384) * 256 + threadIdx.x;
        int j   = idx >> 9;
        int col = (idx & 511) << 2;
        int g   = (j >> 4) & 3;
        int hh  = ((j >> 6) << 4) | (j & 15);
        int r   = g * HIDN + hh;
        const float* src = (col < HIDN) ? (Wx + (int64_t)r * HIDN + col)
                                        : (Wh + (int64_t)r * HIDN + (col - HIDN));
        float4 v = *reinterpret_cast<const float4*>(src);
        ushort4 o;
        o.x = f2bf(v.x); o.y = f2bf(v.y); o.z = f2bf(v.z); o.w = f2bf(v.w);
        *reinterpret_cast<ushort4*>(Bp + (int64_t)j * K_DIM + col) = o;
    }
}

// ---- 128x256 GEMM, 4 waves, BK=32, 48KB LDS -> 2 independent blocks/CU ----
// Per-wave structure identical to verified R3/R6 kernels (offA 8 frags, offB 4,
// acc[8][4], 16 MFMA/phase, swizzle slot ^= (row>>1)&3 both sides: 0 conflicts).
// 4-phase iter (R8 ordering) with re-derived vmcnt ledger (A=2 loads, B=4):
//   ph1: read buf0(mh0)+B; STGA(buf1)<-A(t+1)           [+2]
//   ph2: read buf0(mh1);   STGB(buf0)<-B(t+2); VM4      [+4] -> t+1 landed
//   ph3: read buf1(mh0)+B; STGA(buf0)<-A(t+2)           [+2]
//   ph4: read buf1(mh1);   STGB(buf1)<-B(t+3); VM4      [+4] -> t+2 landed
// (in-flight order at VM4: B_old[4],A_old[2],B_new[4]; vmcnt(4) retires 6.)
// Two blocks per CU have independent barriers -> one block's MFMA covers the
// other's stage/read/barrier windows (m114 co-schedule mechanism).

__device__ __forceinline__ void stg1(unsigned short* dst, const unsigned short* src) {
    __builtin_amdgcn_global_load_lds(
        (const __attribute__((address_space(1))) unsigned int*)src,
        (__attribute__((address_space(3))) unsigned int*)dst, 16, 0, 0);
}

__global__ __launch_bounds__(256, 2) void lstm_gemm_kernel(
    const unsigned short* __restrict__ A, const unsigned short* __restrict__ Bp,
    const float* __restrict__ bx, const float* __restrict__ bh,
    const float* __restrict__ c0, float* __restrict__ out)
{
    __shared__ alignas(16) unsigned short smem[24576];   // 48 KB

    const int tid  = threadIdx.x;
    const int wid  = tid >> 6;
    const int lane = tid & 63;

    // 2D XCD chunking: grid 64(bm) x 16(bn) = 1024; each XCD: 16bm x 8bn.
    const int bid = blockIdx.x;
    const int xcd = bid & 7;
    const int idx = bid >> 3;                 // 0..127
    const int bm  = (xcd & 3) * 16 + (idx & 15);
    const int bn  = (xcd >> 2) * 8 + (idx >> 4);
    const int m0  = bm * BM;
    const int n0  = bn * BN;
    const int wn  = wid;                      // 0..3, 64 cols each

    const unsigned short* Ag = A  + (int64_t)m0 * K_DIM;
    const unsigned short* Bg = Bp + (int64_t)n0 * K_DIM;

    // staging: chunk c -> source (row=c>>2)*K_DIM + swizzled slot; LDS dest
    // wave-uniform base (c&~63)*8 + lane*16 (linear, m104).
    const int cA0 = tid, cA1 = 256 + tid;                       // A: 512 chunks
    const int cB0 = tid, cB1 = 256 + tid, cB2 = 512 + tid, cB3 = 768 + tid; // B: 1024
#define SOFF(c) ((int64_t)((c) >> 2) * K_DIM + (int64_t)((((c) & 3) ^ (((c) >> 3) & 3)) * 8))
#define LDSB(c) (((c) & ~63) * 8)
    const int64_t sA0 = SOFF(cA0), sA1 = SOFF(cA1);
    const int64_t sB0 = SOFF(cB0), sB1 = SOFF(cB1), sB2 = SOFF(cB2), sB3 = SOFF(cB3);
    const int lA0 = LDSB(cA0), lA1 = LDSB(cA1);
    const int lB0 = LDSB(cB0), lB1 = LDSB(cB1), lB2 = LDSB(cB2), lB3 = LDSB(cB3);

    // ds_read fragment offsets (region-relative, shorts) — verified swizzle
    int offA[8], offB[4];
#pragma unroll
    for (int m = 0; m < 8; ++m) {
        const int row = m * 16 + (lane & 15);
        offA[m] = row * 32 + (((lane >> 4) ^ (row >> 1)) & 3) * 8;
    }
#pragma unroll
    for (int n = 0; n < 4; ++n) {
        const int row = wn * 64 + n * 16 + (lane & 15);
        offB[n] = row * 32 + (((lane >> 4) ^ (row >> 1)) & 3) * 8;
    }

    f32x4 acc[8][4] = {};
    bf16x8 aX[4], aY[4], bX[4];

#define REGPA(buf) (smem + (buf) * 12288)
#define REGPB(buf) (smem + (buf) * 12288 + 4096)
#define LOAD_AX(buf, mh) { \
    const unsigned short* r_ = REGPA(buf); \
    _Pragma("unroll") for (int m_ = 0; m_ < 4; ++m_) \
        ((mh) ? aY : aX)[m_] = *reinterpret_cast<const bf16x8*>(r_ + offA[(mh) * 4 + m_]); }
#define LOAD_BX(buf) { \
    const unsigned short* r_ = REGPB(buf); \
    _Pragma("unroll") for (int n_ = 0; n_ < 4; ++n_) \
        bX[n_] = *reinterpret_cast<const bf16x8*>(r_ + offB[n_]); }
#define MFMA16S(aS, mh) { \
    _Pragma("unroll") for (int m_ = 0; m_ < 4; ++m_) \
    _Pragma("unroll") for (int n_ = 0; n_ < 4; ++n_) \
        acc[(mh) * 4 + m_][n_] = __builtin_amdgcn_mfma_f32_16x16x32_bf16(aS[m_], bX[n_], acc[(mh) * 4 + m_][n_], 0, 0, 0); }
#define STGA(buf, gt) { unsigned short* r_ = REGPA(buf); \
    stg1(r_ + lA0, (gt) + sA0); stg1(r_ + lA1, (gt) + sA1); }
#define STGB(buf, gt) { unsigned short* r_ = REGPB(buf); \
    stg1(r_ + lB0, (gt) + sB0); stg1(r_ + lB1, (gt) + sB1); \
    stg1(r_ + lB2, (gt) + sB2); stg1(r_ + lB3, (gt) + sB3); }
#define VM4() asm volatile("s_waitcnt vmcnt(4)" ::: "memory")
#define SB()  { asm volatile("s_waitcnt lgkmcnt(0)" ::: "memory"); \
                __builtin_amdgcn_s_barrier(); \
                __builtin_amdgcn_s_setprio(1); }
#define SE()  { __builtin_amdgcn_s_setprio(0); }

    // ---- prologue: B(t0)[4], A(t0)[2], B(t1)[4]; vmcnt(4) -> t0 landed ----
    STGB(0, Bg);
    STGA(0, Ag);
    STGB(1, Bg + 32);
    asm volatile("s_waitcnt vmcnt(4)" ::: "memory");
    __builtin_amdgcn_s_barrier();

    // ---- main loop: iter i computes tiles 2i (buf0), 2i+1 (buf1) ----
    for (int i = 0; i < NITER - 1; ++i) {
        const unsigned short* At1 = Ag + (2 * i + 1) * 32;
        const unsigned short* At2 = Ag + (2 * i + 2) * 32;
        const unsigned short* Bt2 = Bg + (2 * i + 2) * 32;
        const unsigned short* Bt3 = Bg + (2 * i + 3) * 32;

        // ph1
        LOAD_AX(0, 0); LOAD_BX(0);
        STGA(1, At1);
        SB(); MFMA16S(aX, 0); SE();
        // ph2
        LOAD_AX(0, 1);
        STGB(0, Bt2);
        VM4();
        SB(); MFMA16S(aY, 1); SE();
        // ph3
        LOAD_AX(1, 0); LOAD_BX(1);
        STGA(0, At2);
        SB(); MFMA16S(aX, 0); SE();
        // ph4
        LOAD_AX(1, 1);
        STGB(1, Bt3);
        VM4();
        SB(); MFMA16S(aY, 1); SE();
    }

    // ---- final iter (tiles 62, 63): only t63.A left to stage ----
    {
        LOAD_AX(0, 0); LOAD_BX(0);
        STGA(1, Ag + 63 * 32);
        SB(); MFMA16S(aX, 0); SE();
        LOAD_AX(0, 1);
        asm volatile("s_waitcnt vmcnt(0)" ::: "memory");   // B63 + A63 retired
        SB(); MFMA16S(aY, 1); SE();
        LOAD_AX(1, 0); LOAD_BX(1);
        SB(); MFMA16S(aX, 0); SE();
        LOAD_AX(1, 1);
        SB(); MFMA16S(aY, 1); SE();
    }

    // ---- fused LSTM epilogue ----
    const int h = (n0 >> 2) + wn * 16 + (lane & 15);
    const float bi  = bx[h]            + bh[h];
    const float bff = bx[HIDN + h]     + bh[HIDN + h];
    const float bc  = bx[2 * HIDN + h] + bh[2 * HIDN + h];
    const float bo  = bx[3 * HIDN + h] + bh[3 * HIDN + h];

#pragma unroll
    for (int m = 0; m < 8; ++m) {
        const int rowb = m0 + m * 16 + ((lane >> 4) << 2);
#pragma unroll
        for (int r = 0; r < 4; ++r) {
            const int row = rowb + r;
            const float gi = acc[m][0][r] + bi;
            const float gf = acc[m][1][r] + bff;
            const float gc = acc[m][2][r] + bc;
            const float go = acc[m][3][r] + bo;
            const float si = 1.f / (1.f + __expf(-gi));
            const float sf = 1.f / (1.f + __expf(-gf));
            const float tc = 1.f - 2.f / (__expf(2.f * gc) + 1.f);
            const float so = 1.f / (1.f + __expf(-go));
            const float c0v = c0[(int64_t)row * HIDN + h];
            const float c1 = sf * c0v + si * tc;
            const float th = 1.f - 2.f / (__expf(2.f * c1) + 1.f);
            out[(int64_t)row * HIDN + h] = so * th;                        // h1
            out[(int64_t)M_ROWS * HIDN + (int64_t)row * HIDN + h] = c1;    // c1
        }
    }
}

extern "C" void kernel_launch(void* const* d_in, const int* in_sizes, int n_in,
                              void* d_out, int out_size, void* d_ws, size_t ws_size,
                              hipStream_t stream) {
    const float* x  = (const float*)d_in[0];
    const float* h0 = (const float*)d_in[1];
    const float* c0 = (const float*)d_in[2];
    const float* Wx = (const float*)d_in[3];
    const float* bx = (const float*)d_in[4];
    const float* Wh = (const float*)d_in[5];
    const float* bh = (const float*)d_in[6];
    float* out = (float*)d_out;

    unsigned short* A = (unsigned short*)d_ws;                       // 33.5 MB
    unsigned short* B = A + (size_t)M_ROWS * K_DIM;                  // 16.8 MB

    pack_kernel<<<dim3(24576), dim3(256), 0, stream>>>(x, h0, Wx, Wh, A, B);
    lstm_gemm_kernel<<<dim3(1024), dim3(256), 0, stream>>>(A, B, bx, bh, c0, out);
}

// Round 13
// 157.551 us; speedup vs baseline: 1.0716x; 1.0716x over previous
//
#include <hip/hip_runtime.h>
#include <hip/hip_bf16.h>
#include <stdint.h>

typedef __bf16 bf16x8 __attribute__((ext_vector_type(8)));
typedef float  f32x4  __attribute__((ext_vector_type(4)));

#define M_ROWS 8192
#define K_DIM  2048
#define HIDN   1024
#define BM 256
#define BN 256
#define BK 64
#define NTILES (K_DIM / BK)   /* 32 */
#define NITER  (NTILES / 2)   /* 16 */

__device__ __forceinline__ unsigned short f2bf(float f) {
    __hip_bfloat16 h = __float2bfloat16(f);
    return *reinterpret_cast<unsigned short*>(&h);
}

// ---------------- fused pack kernel (verified) ----------------
__global__ __launch_bounds__(256) void pack_kernel(const float* __restrict__ x,
                                                   const float* __restrict__ h0,
                                                   const float* __restrict__ Wx,
                                                   const float* __restrict__ Wh,
                                                   unsigned short* __restrict__ A,
                                                   unsigned short* __restrict__ Bp) {
    if (blockIdx.x < 16384) {
        int idx = blockIdx.x * 256 + threadIdx.x;
        int row = idx >> 9;
        int col = (idx & 511) << 2;
        const float* src = (col < HIDN) ? (x + (int64_t)row * HIDN + col)
                                        : (h0 + (int64_t)row * HIDN + (col - HIDN));
        float4 v = *reinterpret_cast<const float4*>(src);
        ushort4 o;
        o.x = f2bf(v.x); o.y = f2bf(v.y); o.z = f2bf(v.z); o.w = f2bf(v.w);
        *reinterpret_cast<ushort4*>(A + (int64_t)idx * 4) = o;
    } else {
        int idx = (blockIdx.x - 16384) * 256 + threadIdx.x;
        int j   = idx >> 9;
        int col = (idx & 511) << 2;
        int g   = (j >> 4) & 3;
        int hh  = ((j >> 6) << 4) | (j & 15);
        int r   = g * HIDN + hh;
        const float* src = (col < HIDN) ? (Wx + (int64_t)r * HIDN + col)
                                        : (Wh + (int64_t)r * HIDN + (col - HIDN));
        float4 v = *reinterpret_cast<const float4*>(src);
        ushort4 o;
        o.x = f2bf(v.x); o.y = f2bf(v.y); o.z = f2bf(v.z); o.w = f2bf(v.w);
        *reinterpret_cast<ushort4*>(Bp + (int64_t)j * K_DIM + col) = o;
    }
}

// ---- 256x256 8-phase GEMM, counted-lgkm overlap, NO sched fences ----
// R11 structure minus sched_barrier(0) (m141: order-pinning defeats the
// compiler scheduler). Phase: [bar ; ds_reads ; lgkm(N) ; STG ; VM6(P4/P8) ;
// setprio1 ; MFMA ; setprio0]. FIFO lgkm audit (per wave, per phase):
//  P1 issue 12 (aX4,bX4,aY4), lgkm(4) -> aX,bX done (MFMA uses them), aY in flight
//  P2 issue 8  (aX',bY),      lgkm(8) -> aY done        (MFMA aY,bX)
//  P3 issue 4  (aY'),         lgkm(4) -> P2's done      (MFMA aX',bY)
//  P4 issue 0,                lgkm(0) -> aY' done       (MFMA aY',bY); VM6
//  P5..P8 symmetric on buf1.
// WAR/RAW ledger identical to R11 (verified passing).

__device__ __forceinline__ void stg2(unsigned short* r_, const unsigned short* gt,
                                     int64_t soff0, int64_t soff1, int l0, int l1) {
    __builtin_amdgcn_global_load_lds(
        (const __attribute__((address_space(1))) unsigned int*)(gt + soff0),
        (__attribute__((address_space(3))) unsigned int*)(r_ + l0), 16, 0, 0);
    __builtin_amdgcn_global_load_lds(
        (const __attribute__((address_space(1))) unsigned int*)(gt + soff1),
        (__attribute__((address_space(3))) unsigned int*)(r_ + l1), 16, 0, 0);
}

__global__ __launch_bounds__(512, 2) void lstm_gemm_kernel(
    const unsigned short* __restrict__ A, const unsigned short* __restrict__ Bp,
    const float* __restrict__ bx, const float* __restrict__ bh,
    const float* __restrict__ c0, float* __restrict__ out)
{
    __shared__ alignas(16) unsigned short smem[65536];   // 128 KB

    const int tid  = threadIdx.x;
    const int wid  = tid >> 6;
    const int lane = tid & 63;

    const int bid = blockIdx.x;
    const int xcd = bid & 7;
    const int idx = bid >> 3;            // 0..63
    const int bm  = (xcd & 3) * 8 + (idx & 7);
    const int bn  = (xcd >> 2) * 8 + (idx >> 3);
    const int m0  = bm * BM;
    const int n0  = bn * BN;
    const int wm  = wid >> 2;            // 0..1
    const int wn  = wid & 3;             // 0..3

    const unsigned short* Ag = A  + (int64_t)m0 * K_DIM;
    const unsigned short* Bg = Bp + (int64_t)n0 * K_DIM;

    const int c0_ = wid * 64 + lane;
    const int c1_ = 512 + c0_;
    const int64_t soff0 = (int64_t)(c0_ >> 2) * K_DIM + (int64_t)((((c0_ & 3) ^ ((c0_ >> 3) & 3))) * 8);
    const int64_t soff1 = (int64_t)(c1_ >> 2) * K_DIM + (int64_t)((((c1_ & 3) ^ ((c1_ >> 3) & 3))) * 8);
    const int l0 = (c0_ & ~63) * 8;
    const int l1 = (c1_ & ~63) * 8;

    int offA[8], offB[4];
#pragma unroll
    for (int m = 0; m < 8; ++m) {
        const int row = wm * 128 + m * 16 + (lane & 15);
        offA[m] = row * 32 + (((lane >> 4) ^ (row >> 1)) & 3) * 8;
    }
#pragma unroll
    for (int n = 0; n < 4; ++n) {
        const int row = wn * 64 + n * 16 + (lane & 15);
        offB[n] = row * 32 + (((lane >> 4) ^ (row >> 1)) & 3) * 8;
    }

    f32x4 acc[8][4] = {};
    bf16x8 aX[4], aY[4], bX[4], bY[4];

#define REGP(buf, mat, kh) (smem + (buf) * 32768 + (mat) * 16384 + (kh) * 8192)
#define LOAD_AS(S, buf, kh, mh) { \
    const unsigned short* r_ = REGP(buf, 0, kh); \
    _Pragma("unroll") for (int m_ = 0; m_ < 4; ++m_) \
        S[m_] = *reinterpret_cast<const bf16x8*>(r_ + offA[(mh) * 4 + m_]); }
#define LOAD_BS(S, buf, kh) { \
    const unsigned short* r_ = REGP(buf, 1, kh); \
    _Pragma("unroll") for (int n_ = 0; n_ < 4; ++n_) \
        S[n_] = *reinterpret_cast<const bf16x8*>(r_ + offB[n_]); }
#define MFMA16S(aS, bS, mh) { \
    _Pragma("unroll") for (int m_ = 0; m_ < 4; ++m_) \
    _Pragma("unroll") for (int n_ = 0; n_ < 4; ++n_) \
        acc[(mh) * 4 + m_][n_] = __builtin_amdgcn_mfma_f32_16x16x32_bf16(aS[m_], bS[n_], acc[(mh) * 4 + m_][n_], 0, 0, 0); }
#define STG(buf, mat, kh, gt) stg2(REGP(buf, mat, kh), (gt), soff0, soff1, l0, l1)
#define BAR() __builtin_amdgcn_s_barrier()
#define VM6() asm volatile("s_waitcnt vmcnt(6)" ::: "memory")
#define LGKM(N) asm volatile("s_waitcnt lgkmcnt(" #N ")" ::: "memory")
#define P1() __builtin_amdgcn_s_setprio(1)
#define P0() __builtin_amdgcn_s_setprio(0)

    // ---- prologue (STG order identical to R6-verified) ----
    STG(0, 1, 0, Bg);            // t0.B-kh0
    STG(0, 0, 0, Ag);            // t0.A-kh0
    STG(0, 1, 1, Bg + 32);       // t0.B-kh1
    STG(0, 0, 1, Ag + 32);       // t0.A-kh1
    asm volatile("s_waitcnt vmcnt(4)" ::: "memory");
    STG(1, 1, 0, Bg + 64);       // t1.B-kh0
    STG(1, 0, 0, Ag + 64);       // t1.A-kh0
    STG(1, 1, 1, Bg + 96);       // t1.B-kh1
    asm volatile("s_waitcnt vmcnt(6)" ::: "memory");   // all t0 landed

    // ---- main loop ----
    for (int i = 0; i < NITER - 1; ++i) {
        const unsigned short* At1 = Ag + (2 * i + 1) * 64;
        const unsigned short* At2 = Ag + (2 * i + 2) * 64;
        const unsigned short* At3 = Ag + (2 * i + 3) * 64;
        const unsigned short* Bt2 = Bg + (2 * i + 2) * 64;
        const unsigned short* Bt3 = Bg + (2 * i + 3) * 64;

        // P1: operands (0,kh0) + prefetch aY; lgkm(4) leaves aY in flight
        BAR();
        LOAD_AS(aX, 0, 0, 0); LOAD_BS(bX, 0, 0);
        LOAD_AS(aY, 0, 0, 1);
        LGKM(4);
        STG(1, 0, 1, At1 + 32);
        P1(); MFMA16S(aX, bX, 0); P0();
        // P2
        BAR();
        LOAD_AS(aX, 0, 1, 0); LOAD_BS(bY, 0, 1);
        LGKM(8);
        STG(0, 1, 0, Bt2);
        P1(); MFMA16S(aY, bX, 1); P0();
        // P3
        BAR();
        LOAD_AS(aY, 0, 1, 1);
        LGKM(4);
        STG(0, 0, 0, At2);
        P1(); MFMA16S(aX, bY, 0); P0();
        // P4: VM6 -> t(2i+1) landed after this barrier
        BAR();
        LGKM(0);
        STG(0, 1, 1, Bt2 + 32);
        VM6();
        P1(); MFMA16S(aY, bY, 1); P0();
        // P5
        BAR();
        LOAD_AS(aX, 1, 0, 0); LOAD_BS(bX, 1, 0);
        LOAD_AS(aY, 1, 0, 1);
        LGKM(4);
        STG(0, 0, 1, At2 + 32);
        P1(); MFMA16S(aX, bX, 0); P0();
        // P6
        BAR();
        LOAD_AS(aX, 1, 1, 0); LOAD_BS(bY, 1, 1);
        LGKM(8);
        STG(1, 1, 0, Bt3);
        P1(); MFMA16S(aY, bX, 1); P0();
        // P7
        BAR();
        LOAD_AS(aY, 1, 1, 1);
        LGKM(4);
        STG(1, 0, 0, At3);
        P1(); MFMA16S(aX, bY, 0); P0();
        // P8: VM6 -> t(2i+2) landed after this barrier
        BAR();
        LGKM(0);
        STG(1, 1, 1, Bt3 + 32);
        VM6();
        P1(); MFMA16S(aY, bY, 1); P0();
    }

    // ---- final iteration (tiles 30, 31): only t31.A-kh1 left to stage ----
    {
        BAR();
        LOAD_AS(aX, 0, 0, 0); LOAD_BS(bX, 0, 0);
        LOAD_AS(aY, 0, 0, 1);
        LGKM(4);
        STG(1, 0, 1, Ag + 31 * 64 + 32);
        P1(); MFMA16S(aX, bX, 0); P0();
        BAR();
        LOAD_AS(aX, 0, 1, 0); LOAD_BS(bY, 0, 1);
        LGKM(8);
        P1(); MFMA16S(aY, bX, 1); P0();
        BAR();
        LOAD_AS(aY, 0, 1, 1);
        LGKM(4);
        P1(); MFMA16S(aX, bY, 0); P0();
        BAR();
        LGKM(0);
        asm volatile("s_waitcnt vmcnt(0)" ::: "memory");   // t31 fully landed
        P1(); MFMA16S(aY, bY, 1); P0();
        BAR();
        LOAD_AS(aX, 1, 0, 0); LOAD_BS(bX, 1, 0);
        LOAD_AS(aY, 1, 0, 1);
        LGKM(4);
        P1(); MFMA16S(aX, bX, 0); P0();
        BAR();
        LOAD_AS(aX, 1, 1, 0); LOAD_BS(bY, 1, 1);
        LGKM(8);
        P1(); MFMA16S(aY, bX, 1); P0();
        BAR();
        LOAD_AS(aY, 1, 1, 1);
        LGKM(4);
        P1(); MFMA16S(aX, bY, 0); P0();
        BAR();
        LGKM(0);
        P1(); MFMA16S(aY, bY, 1); P0();
    }

    // ---- fused LSTM epilogue ----
    const int h = (n0 >> 2) + wn * 16 + (lane & 15);
    const float bi  = bx[h]            + bh[h];
    const float bff = bx[HIDN + h]     + bh[HIDN + h];
    const float bc  = bx[2 * HIDN + h] + bh[2 * HIDN + h];
    const float bo  = bx[3 * HIDN + h] + bh[3 * HIDN + h];

#pragma unroll
    for (int m = 0; m < 8; ++m) {
        const int rowb = m0 + wm * 128 + m * 16 + ((lane >> 4) << 2);
#pragma unroll
        for (int r = 0; r < 4; ++r) {
            const int row = rowb + r;
            const float gi = acc[m][0][r] + bi;
            const float gf = acc[m][1][r] + bff;
            const float gc = acc[m][2][r] + bc;
            const float go = acc[m][3][r] + bo;
            const float si = 1.f / (1.f + __expf(-gi));
            const float sf = 1.f / (1.f + __expf(-gf));
            const float tc = 1.f - 2.f / (__expf(2.f * gc) + 1.f);
            const float so = 1.f / (1.f + __expf(-go));
            const float c0v = c0[(int64_t)row * HIDN + h];
            const float c1 = sf * c0v + si * tc;
            const float th = 1.f - 2.f / (__expf(2.f * c1) + 1.f);
            out[(int64_t)row * HIDN + h] = so * th;                        // h1
            out[(int64_t)M_ROWS * HIDN + (int64_t)row * HIDN + h] = c1;    // c1
        }
    }
}

extern "C" void kernel_launch(void* const* d_in, const int* in_sizes, int n_in,
                              void* d_out, int out_size, void* d_ws, size_t ws_size,
                              hipStream_t stream) {
    const float* x  = (const float*)d_in[0];
    const float* h0 = (const float*)d_in[1];
    const float* c0 = (const float*)d_in[2];
    const float* Wx = (const float*)d_in[3];
    const float* bx = (const float*)d_in[4];
    const float* Wh = (const float*)d_in[5];
    const float* bh = (const float*)d_in[6];
    float* out = (float*)d_out;

    unsigned short* A = (unsigned short*)d_ws;                       // 33.5 MB
    unsigned short* B = A + (size_t)M_ROWS * K_DIM;                  // 16.8 MB

    pack_kernel<<<dim3(24576), dim3(256), 0, stream>>>(x, h0, Wx, Wh, A, B);
    lstm_gemm_kernel<<<dim3(512), dim3(512), 0, stream>>>(A, B, bx, bh, c0, out);
}